// Round 1
// baseline (330.732 us; speedup 1.0000x reference)
//
#include <hip/hip_runtime.h>
#include <math.h>

// Problem constants: B=1024, D=1024 -> tokens N_TOK=4096, EMB=256, CODES=512.
// d_out layout (float32): out[1048576], loss[1], idx_as_float[4096].

// ---------------------------------------------------------------------------
// Generic fp32 tiled GEMM: C = act(A @ B + bias)
//  A: [M,K] row-major.  B: NN -> [K,N] row-major; NT -> [N,K] row-major.
//  BM=BN=64, BK=16, 256 threads, 4x4 micro-tile per thread.
// ---------------------------------------------------------------------------
template <bool RELU, bool TRANSB>
__global__ __launch_bounds__(256) void sgemm64(
    const float* __restrict__ A, const float* __restrict__ B,
    const float* __restrict__ bias, float* __restrict__ C,
    int M, int N, int K)
{
    constexpr int BM = 64, BN = 64, BK = 16;
    __shared__ float As[BK][BM + 4];   // pad -> 68 floats (272B, 16B-aligned rows)
    __shared__ float Bs[BK][BN + 4];

    const int tid = threadIdx.x;
    const int m0 = blockIdx.y * BM;
    const int n0 = blockIdx.x * BN;

    // A-tile (and NT B-tile) loader mapping: one float4 along K per thread
    const int la_m = tid >> 2;          // 0..63 row within tile
    const int la_k = (tid & 3) * 4;     // 0,4,8,12
    // NN B-tile loader mapping: one float4 along N per thread
    const int lb_r = tid >> 4;          // 0..15 k-row
    const int lb_c = (tid & 15) * 4;    // 0..60 n-col

    const int tm = (tid >> 4) * 4;      // micro-tile row base
    const int tn = (tid & 15) * 4;      // micro-tile col base

    float acc[4][4] = {{0.f}};

    for (int k0 = 0; k0 < K; k0 += BK) {
        float4 a4 = *reinterpret_cast<const float4*>(
            &A[(size_t)(m0 + la_m) * K + k0 + la_k]);
        As[la_k + 0][la_m] = a4.x;
        As[la_k + 1][la_m] = a4.y;
        As[la_k + 2][la_m] = a4.z;
        As[la_k + 3][la_m] = a4.w;
        if (!TRANSB) {
            float4 b4 = *reinterpret_cast<const float4*>(
                &B[(size_t)(k0 + lb_r) * N + n0 + lb_c]);
            *reinterpret_cast<float4*>(&Bs[lb_r][lb_c]) = b4;
        } else {
            float4 b4 = *reinterpret_cast<const float4*>(
                &B[(size_t)(n0 + la_m) * K + k0 + la_k]);
            Bs[la_k + 0][la_m] = b4.x;
            Bs[la_k + 1][la_m] = b4.y;
            Bs[la_k + 2][la_m] = b4.z;
            Bs[la_k + 3][la_m] = b4.w;
        }
        __syncthreads();

        #pragma unroll
        for (int k = 0; k < BK; ++k) {
            float4 av = *reinterpret_cast<const float4*>(&As[k][tm]);
            float4 bv = *reinterpret_cast<const float4*>(&Bs[k][tn]);
            float a[4] = {av.x, av.y, av.z, av.w};
            float b[4] = {bv.x, bv.y, bv.z, bv.w};
            #pragma unroll
            for (int i = 0; i < 4; ++i)
                #pragma unroll
                for (int j = 0; j < 4; ++j)
                    acc[i][j] = fmaf(a[i], b[j], acc[i][j]);
        }
        __syncthreads();
    }

    float bx[4] = {0.f, 0.f, 0.f, 0.f};
    if (bias) {
        float4 bv = *reinterpret_cast<const float4*>(&bias[n0 + tn]);
        bx[0] = bv.x; bx[1] = bv.y; bx[2] = bv.z; bx[3] = bv.w;
    }
    #pragma unroll
    for (int i = 0; i < 4; ++i) {
        float4 o;
        float v0 = acc[i][0] + bx[0];
        float v1 = acc[i][1] + bx[1];
        float v2 = acc[i][2] + bx[2];
        float v3 = acc[i][3] + bx[3];
        if (RELU) {
            v0 = fmaxf(v0, 0.f); v1 = fmaxf(v1, 0.f);
            v2 = fmaxf(v2, 0.f); v3 = fmaxf(v3, 0.f);
        }
        o.x = v0; o.y = v1; o.z = v2; o.w = v3;
        *reinterpret_cast<float4*>(&C[(size_t)(m0 + tm + i) * N + n0 + tn]) = o;
    }
}

// ---------------------------------------------------------------------------
// cnorm[k] = ||codebook[k]||^2   (one wave per code)
// ---------------------------------------------------------------------------
__global__ void cnorm_kernel(const float* __restrict__ CB, float* __restrict__ cnorm)
{
    const int k = blockIdx.x;
    const int lane = threadIdx.x;  // 64
    float4 c4 = *reinterpret_cast<const float4*>(&CB[(size_t)k * 256 + lane * 4]);
    float s = c4.x * c4.x + c4.y * c4.y + c4.z * c4.z + c4.w * c4.w;
    #pragma unroll
    for (int off = 32; off; off >>= 1) s += __shfl_down(s, off);
    if (lane == 0) cnorm[k] = s;
}

// ---------------------------------------------------------------------------
// Per-token: argmin_k (cnorm[k] - 2*S[n,k]), gather codebook row to out,
// accumulate loss_sum += ||z_n||^2 + min_val  (= ||z_n - q||^2), idx as float.
// One wave (64 threads) per token.
// ---------------------------------------------------------------------------
__global__ void vq_kernel(const float* __restrict__ Z, const float* __restrict__ S,
                          const float* __restrict__ CB, const float* __restrict__ cnorm,
                          float* __restrict__ out, float* __restrict__ loss_sum,
                          float* __restrict__ idx_out)
{
    const int n = blockIdx.x;
    const int lane = threadIdx.x;  // 64

    float best = 3.4e38f;
    int bidx = 0x7fffffff;
    #pragma unroll
    for (int j = 0; j < 8; ++j) {
        const int k = j * 64 + lane;                   // increasing k per lane
        float v = fmaf(-2.0f, S[(size_t)n * 512 + k], cnorm[k]);
        if (v < best) { best = v; bidx = k; }          // strict < keeps first occurrence
    }
    #pragma unroll
    for (int off = 32; off; off >>= 1) {
        float ov = __shfl_down(best, off);
        int oi = __shfl_down(bidx, off);
        if (ov < best || (ov == best && oi < bidx)) { best = ov; bidx = oi; }
    }
    bidx = __shfl(bidx, 0);
    best = __shfl(best, 0);

    // ||z_n||^2 partial + reduce
    float4 z4 = *reinterpret_cast<const float4*>(&Z[(size_t)n * 256 + lane * 4]);
    float zn = z4.x * z4.x + z4.y * z4.y + z4.z * z4.z + z4.w * z4.w;
    #pragma unroll
    for (int off = 32; off; off >>= 1) zn += __shfl_down(zn, off);

    // gather nearest code and write straight-through output
    float4 q4 = *reinterpret_cast<const float4*>(&CB[(size_t)bidx * 256 + lane * 4]);
    *reinterpret_cast<float4*>(&out[(size_t)n * 256 + lane * 4]) = q4;

    if (lane == 0) {
        atomicAdd(loss_sum, zn + best);   // = ||z - q||^2 for this token
        idx_out[n] = (float)bidx;
    }
}

__global__ void finalize_kernel(const float* __restrict__ loss_sum,
                                float* __restrict__ loss_out)
{
    // loss = codebook_loss + 0.25*commitment = 1.25 * mean((q-z)^2)
    loss_out[0] = 1.25f * loss_sum[0] / 1048576.0f;
}

// ---------------------------------------------------------------------------
extern "C" void kernel_launch(void* const* d_in, const int* in_sizes, int n_in,
                              void* d_out, int out_size, void* d_ws, size_t ws_size,
                              hipStream_t stream)
{
    const float* obs = (const float*)d_in[0];
    const float* W1  = (const float*)d_in[1];
    const float* b1  = (const float*)d_in[2];
    const float* W2  = (const float*)d_in[3];
    const float* b2  = (const float*)d_in[4];
    const float* W3  = (const float*)d_in[5];
    const float* b3  = (const float*)d_in[6];
    const float* CB  = (const float*)d_in[7];

    float* out = (float*)d_out;                 // [1048576] quantized
    float* loss_out = out + 1048576;            // [1]
    float* idx_out  = out + 1048577;            // [4096] as float

    float* ws = (float*)d_ws;
    float* H1 = ws;                             // 1M floats (4MB)
    float* H2 = ws + (1 << 20);                 // 4MB
    float* F  = ws;                             // reuse H1 slot (H1 dead after GEMM2)
    float* S  = ws + (1 << 20);                 // 8MB, overwrites H2 (dead after GEMM3)
    float* cn = ws + 3 * (1 << 20);             // 512 floats
    float* ls = cn + 512;                       // 1 float accumulator

    dim3 blk(256);
    // MLP: three 1024^3 GEMMs (fp32, VALU)
    sgemm64<true,  false><<<dim3(16, 16), blk, 0, stream>>>(obs, W1, b1, H1, 1024, 1024, 1024);
    sgemm64<true,  false><<<dim3(16, 16), blk, 0, stream>>>(H1,  W2, b2, H2, 1024, 1024, 1024);
    sgemm64<false, false><<<dim3(16, 16), blk, 0, stream>>>(H2,  W3, b3, F,  1024, 1024, 1024);

    // code norms
    cnorm_kernel<<<512, 64, 0, stream>>>(CB, cn);

    // S = z @ codebook^T : [4096, 512], K=256  (NT layout)
    sgemm64<false, true><<<dim3(8, 64), blk, 0, stream>>>(F, CB, nullptr, S, 4096, 512, 256);

    // loss accumulator zero + VQ (argmin, gather, loss)
    hipMemsetAsync(ls, 0, sizeof(float), stream);
    vq_kernel<<<4096, 64, 0, stream>>>(F, S, CB, cn, out, ls, idx_out);

    finalize_kernel<<<1, 1, 0, stream>>>(ls, loss_out);
}

// Round 2
// 300.287 us; speedup vs baseline: 1.1014x; 1.1014x over previous
//
#include <hip/hip_runtime.h>
#include <math.h>

// B=1024, D=1024 -> tokens N_TOK=4096, EMB=256, CODES=512.
// d_out (float32): out[1048576], loss[1], idx_as_float[4096].

typedef _Float16 half8 __attribute__((ext_vector_type(8)));
typedef _Float16 half4 __attribute__((ext_vector_type(4)));
typedef float floatx4 __attribute__((ext_vector_type(4)));

#define LO_SCALE 2048.0f
#define INV_LO_SCALE (1.0f / 2048.0f)

// ---------------------------------------------------------------------------
// Stage one 64x64 f16 tile (rows r0.., cols kb..kb+63 of a [R][ldk] matrix)
// into LDS with the MFMA-stacked-k permutation + XOR-16B-granule swizzle.
// Layout: per row (64 halves = 8 granules of 16B). Granule (ks*4+g)^(row&7)
// holds halves [h=0: j0..3][h=1: j0..3] for k = ks*32 + 16h + 4g + j.
// ---------------------------------------------------------------------------
__device__ __forceinline__ void stage_tile(
    const _Float16* __restrict__ G, int ldk, int r0, int kb,
    _Float16* __restrict__ lds, int tid)
{
    const int so = tid & 7;        // octet: k_local = so*8 + e
    const int sr = tid >> 3;       // rows sr and sr+32
    const int ks = so >> 2;
    const int hh = (so >> 1) & 1;  // stacked half
    const int g0 = (so & 1) * 2;   // granule pair base
    #pragma unroll
    for (int rr = 0; rr < 64; rr += 32) {
        const int row = sr + rr;
        half8 v = *reinterpret_cast<const half8*>(
            &G[(size_t)(r0 + row) * ldk + kb + so * 8]);
        const int sw = row & 7;
        const int base = row * 64;
        const int gr1 = (ks * 4 + g0) ^ sw;
        const int gr2 = (ks * 4 + g0 + 1) ^ sw;
        half4 a, b;
        #pragma unroll
        for (int j = 0; j < 4; ++j) { a[j] = v[j]; b[j] = v[j + 4]; }
        *reinterpret_cast<half4*>(&lds[base + gr1 * 8 + hh * 4]) = a;
        *reinterpret_cast<half4*>(&lds[base + gr2 * 8 + hh * 4]) = b;
    }
}

__device__ __forceinline__ half8 read_frag(
    const _Float16* __restrict__ lds, int row, int ks, int g)
{
    const int gr = (ks * 4 + g) ^ (row & 7);
    return *reinterpret_cast<const half8*>(&lds[row * 64 + gr * 8]);
}

// ---------------------------------------------------------------------------
// C = act(A @ B^T + bias) with fp16 3-term split emulating fp32.
// A: hi/lo [M][K] f16.  B: hi/lo [N][K] f16 (pre-transposed).
// Block: 256 thr / 4 waves, tile 64x64, wave tile 32x32 (2x2 of 16x16x32).
// ---------------------------------------------------------------------------
template <bool RELU, bool WRITE_F32, bool WRITE_SPLIT>
__global__ __launch_bounds__(256) void gemm_f16s3(
    const _Float16* __restrict__ Ah, const _Float16* __restrict__ Al,
    const _Float16* __restrict__ Bh, const _Float16* __restrict__ Bl,
    const float* __restrict__ bias,
    float* __restrict__ Cf, _Float16* __restrict__ Ch, _Float16* __restrict__ Cl,
    int M, int N, int K)
{
    __shared__ __align__(16) _Float16 sAh[64 * 64], sAl[64 * 64];
    __shared__ __align__(16) _Float16 sBh[64 * 64], sBl[64 * 64];

    const int tid = threadIdx.x;
    const int m0 = blockIdx.y * 64, n0 = blockIdx.x * 64;
    const int w = tid >> 6, l = tid & 63;
    const int wm = (w >> 1) * 32, wn = (w & 1) * 32;
    const int fr = l & 15;   // frag row (A) / col (B) / col (C)
    const int fg = l >> 4;   // k-group, also C row group

    floatx4 acc_hh[2][2] = {};
    floatx4 acc_mx[2][2] = {};

    for (int kb = 0; kb < K; kb += 64) {
        if (kb) __syncthreads();
        stage_tile(Ah, K, m0, kb, sAh, tid);
        stage_tile(Al, K, m0, kb, sAl, tid);
        stage_tile(Bh, K, n0, kb, sBh, tid);
        stage_tile(Bl, K, n0, kb, sBl, tid);
        __syncthreads();

        #pragma unroll
        for (int ks = 0; ks < 2; ++ks) {
            half8 ah[2], al[2], bh[2], bl[2];
            #pragma unroll
            for (int i = 0; i < 2; ++i) {
                const int ra = wm + i * 16 + fr;
                const int rb = wn + i * 16 + fr;
                ah[i] = read_frag(sAh, ra, ks, fg);
                al[i] = read_frag(sAl, ra, ks, fg);
                bh[i] = read_frag(sBh, rb, ks, fg);
                bl[i] = read_frag(sBl, rb, ks, fg);
            }
            #pragma unroll
            for (int i = 0; i < 2; ++i)
                #pragma unroll
                for (int j = 0; j < 2; ++j) {
                    acc_hh[i][j] = __builtin_amdgcn_mfma_f32_16x16x32_f16(
                        ah[i], bh[j], acc_hh[i][j], 0, 0, 0);
                    acc_mx[i][j] = __builtin_amdgcn_mfma_f32_16x16x32_f16(
                        ah[i], bl[j], acc_mx[i][j], 0, 0, 0);
                    acc_mx[i][j] = __builtin_amdgcn_mfma_f32_16x16x32_f16(
                        al[i], bh[j], acc_mx[i][j], 0, 0, 0);
                }
        }
    }

    // Epilogue. C/D layout (verified): col = lane&15, row = (lane>>4)*4 + reg.
    #pragma unroll
    for (int i = 0; i < 2; ++i) {
        #pragma unroll
        for (int j = 0; j < 2; ++j) {
            const int col = n0 + wn + j * 16 + fr;
            const float bv = bias ? bias[col] : 0.0f;
            #pragma unroll
            for (int r = 0; r < 4; ++r) {
                const int row = m0 + wm + i * 16 + fg * 4 + r;
                float v = acc_hh[i][j][r] + acc_mx[i][j][r] * INV_LO_SCALE + bv;
                if (RELU) v = fmaxf(v, 0.0f);
                const size_t o = (size_t)row * N + col;
                if (WRITE_F32) Cf[o] = v;
                if (WRITE_SPLIT) {
                    const _Float16 h = (_Float16)v;
                    Ch[o] = h;
                    Cl[o] = (_Float16)((v - (float)h) * LO_SCALE);
                }
            }
        }
    }
}

// ---------------------------------------------------------------------------
// Split fp32 -> f16 hi/lo (no transpose). n must be multiple of 2048.
// ---------------------------------------------------------------------------
__global__ void split_kernel(const float* __restrict__ X,
                             _Float16* __restrict__ H, _Float16* __restrict__ L)
{
    const int i = (blockIdx.x * 256 + threadIdx.x) * 8;
    float4 a = *reinterpret_cast<const float4*>(&X[i]);
    float4 b = *reinterpret_cast<const float4*>(&X[i + 4]);
    float xs[8] = {a.x, a.y, a.z, a.w, b.x, b.y, b.z, b.w};
    half8 h, lo;
    #pragma unroll
    for (int j = 0; j < 8; ++j) {
        const _Float16 hi = (_Float16)xs[j];
        h[j] = hi;
        lo[j] = (_Float16)((xs[j] - (float)hi) * LO_SCALE);
    }
    *reinterpret_cast<half8*>(&H[i]) = h;
    *reinterpret_cast<half8*>(&L[i]) = lo;
}

// ---------------------------------------------------------------------------
// Split + transpose: W [1024][1024] fp32 -> Th/Tl [N][K] f16.
// ---------------------------------------------------------------------------
__global__ __launch_bounds__(256) void splitT_kernel(
    const float* __restrict__ Wm, _Float16* __restrict__ Th, _Float16* __restrict__ Tl)
{
    __shared__ float tile[64][65];
    const int tid = threadIdx.x;
    const int kb = blockIdx.y * 64, nb = blockIdx.x * 64;
    {
        const int kr = tid >> 2, c0 = (tid & 3) * 16;
        #pragma unroll
        for (int c = 0; c < 16; c += 4) {
            float4 v = *reinterpret_cast<const float4*>(
                &Wm[(size_t)(kb + kr) * 1024 + nb + c0 + c]);
            tile[kr][c0 + c] = v.x; tile[kr][c0 + c + 1] = v.y;
            tile[kr][c0 + c + 2] = v.z; tile[kr][c0 + c + 3] = v.w;
        }
    }
    __syncthreads();
    {
        const int nr = tid >> 2, k0 = (tid & 3) * 16;
        half8 h[2], lo[2];
        #pragma unroll
        for (int c = 0; c < 16; ++c) {
            const float x = tile[k0 + c][nr];
            const _Float16 hi = (_Float16)x;
            h[c >> 3][c & 7] = hi;
            lo[c >> 3][c & 7] = (_Float16)((x - (float)hi) * LO_SCALE);
        }
        const size_t o = (size_t)(nb + nr) * 1024 + kb + k0;
        *reinterpret_cast<half8*>(&Th[o]) = h[0];
        *reinterpret_cast<half8*>(&Th[o + 8]) = h[1];
        *reinterpret_cast<half8*>(&Tl[o]) = lo[0];
        *reinterpret_cast<half8*>(&Tl[o + 8]) = lo[1];
    }
}

// ---------------------------------------------------------------------------
// Codebook: split to f16 hi/lo + squared norms. One wave per code.
// ---------------------------------------------------------------------------
__global__ void cb_split_kernel(const float* __restrict__ CB,
                                _Float16* __restrict__ CBh, _Float16* __restrict__ CBl,
                                float* __restrict__ cnorm)
{
    const int k = blockIdx.x, lane = threadIdx.x;  // 64
    const int i = k * 256 + lane * 4;
    float4 c = *reinterpret_cast<const float4*>(&CB[i]);
    float xs[4] = {c.x, c.y, c.z, c.w};
    half4 h, lo;
    float s = 0.f;
    #pragma unroll
    for (int j = 0; j < 4; ++j) {
        const _Float16 hi = (_Float16)xs[j];
        h[j] = hi;
        lo[j] = (_Float16)((xs[j] - (float)hi) * LO_SCALE);
        s += xs[j] * xs[j];
    }
    *reinterpret_cast<half4*>(&CBh[i]) = h;
    *reinterpret_cast<half4*>(&CBl[i]) = lo;
    #pragma unroll
    for (int off = 32; off; off >>= 1) s += __shfl_down(s, off);
    if (lane == 0) cnorm[k] = s;
}

// ---------------------------------------------------------------------------
// VQ: per token argmin_k (cnorm[k] - 2 S[n,k]), gather, loss. 4 tokens/block.
// ---------------------------------------------------------------------------
__global__ __launch_bounds__(256) void vq_kernel(
    const float* __restrict__ Z, const float* __restrict__ S,
    const float* __restrict__ CB, const float* __restrict__ cnorm,
    float* __restrict__ out, float* __restrict__ loss_sum,
    float* __restrict__ idx_out)
{
    const int n = blockIdx.x * 4 + (threadIdx.x >> 6);
    const int lane = threadIdx.x & 63;

    float best = 3.4e38f;
    int bidx = 0x7fffffff;
    #pragma unroll
    for (int j = 0; j < 8; ++j) {
        const int k = j * 64 + lane;
        const float v = fmaf(-2.0f, S[(size_t)n * 512 + k], cnorm[k]);
        if (v < best) { best = v; bidx = k; }   // strict < keeps first occurrence
    }
    #pragma unroll
    for (int off = 32; off; off >>= 1) {
        const float ov = __shfl_down(best, off);
        const int oi = __shfl_down(bidx, off);
        if (ov < best || (ov == best && oi < bidx)) { best = ov; bidx = oi; }
    }
    bidx = __shfl(bidx, 0);
    best = __shfl(best, 0);

    float4 z4 = *reinterpret_cast<const float4*>(&Z[(size_t)n * 256 + lane * 4]);
    float zn = z4.x * z4.x + z4.y * z4.y + z4.z * z4.z + z4.w * z4.w;
    #pragma unroll
    for (int off = 32; off; off >>= 1) zn += __shfl_down(zn, off);

    float4 q4 = *reinterpret_cast<const float4*>(&CB[(size_t)bidx * 256 + lane * 4]);
    *reinterpret_cast<float4*>(&out[(size_t)n * 256 + lane * 4]) = q4;

    if (lane == 0) {
        atomicAdd(loss_sum, zn + best);
        idx_out[n] = (float)bidx;
    }
}

__global__ void finalize_kernel(const float* __restrict__ loss_sum,
                                float* __restrict__ loss_out)
{
    loss_out[0] = 1.25f * loss_sum[0] / 1048576.0f;
}

// ---------------------------------------------------------------------------
extern "C" void kernel_launch(void* const* d_in, const int* in_sizes, int n_in,
                              void* d_out, int out_size, void* d_ws, size_t ws_size,
                              hipStream_t stream)
{
    const float* obs = (const float*)d_in[0];
    const float* W1  = (const float*)d_in[1];
    const float* b1  = (const float*)d_in[2];
    const float* W2  = (const float*)d_in[3];
    const float* b2  = (const float*)d_in[4];
    const float* W3  = (const float*)d_in[5];
    const float* b3  = (const float*)d_in[6];
    const float* CB  = (const float*)d_in[7];

    float* out = (float*)d_out;
    float* loss_out = out + 1048576;
    float* idx_out  = out + 1048577;

    // Workspace layout (byte offsets), lifetimes arranged for reuse:
    char* W = (char*)d_ws;
    float*     F_f32 = (float*)(W + 0);                       // 0..4MB (L3 out)
    _Float16*  O_h   = (_Float16*)(W + (4u  << 20));          // obs split
    _Float16*  O_l   = (_Float16*)(W + (6u  << 20));
    _Float16*  W3t_h = O_h;                                   // after L1
    _Float16*  W3t_l = O_l;
    _Float16*  W1t_h = (_Float16*)(W + (8u  << 20));
    _Float16*  W1t_l = (_Float16*)(W + (10u << 20));
    _Float16*  H2_h  = W1t_h;                                 // after L1
    _Float16*  H2_l  = W1t_l;
    float*     S     = (float*)(W + (4u << 20));              // 4..12MB after L3
    _Float16*  H1_h  = (_Float16*)(W + (12u << 20));
    _Float16*  H1_l  = (_Float16*)(W + (14u << 20));
    _Float16*  F_h   = H1_h;                                  // after L2
    _Float16*  F_l   = H1_l;
    _Float16*  W2t_h = (_Float16*)(W + (16u << 20));
    _Float16*  W2t_l = (_Float16*)(W + (18u << 20));
    _Float16*  CB_h  = (_Float16*)(W + (20u << 20));
    _Float16*  CB_l  = (_Float16*)(W + (20u << 20) + 512 * 256 * 2);
    float*     cn    = (float*)(W + (20u << 20) + 2 * 512 * 256 * 2);
    float*     ls    = cn + 512;

    const dim3 blk(256);

    split_kernel<<<512, blk, 0, stream>>>(obs, O_h, O_l);
    splitT_kernel<<<dim3(16, 16), blk, 0, stream>>>(W1, W1t_h, W1t_l);
    splitT_kernel<<<dim3(16, 16), blk, 0, stream>>>(W2, W2t_h, W2t_l);
    cb_split_kernel<<<512, 64, 0, stream>>>(CB, CB_h, CB_l, cn);
    hipMemsetAsync(ls, 0, sizeof(float), stream);

    // L1: H1 = relu(obs @ W1 + b1), split output only
    gemm_f16s3<true, false, true><<<dim3(16, 16), blk, 0, stream>>>(
        O_h, O_l, W1t_h, W1t_l, b1, nullptr, H1_h, H1_l, 1024, 1024, 1024);
    splitT_kernel<<<dim3(16, 16), blk, 0, stream>>>(W3, W3t_h, W3t_l);
    // L2
    gemm_f16s3<true, false, true><<<dim3(16, 16), blk, 0, stream>>>(
        H1_h, H1_l, W2t_h, W2t_l, b2, nullptr, H2_h, H2_l, 1024, 1024, 1024);
    // L3: F fp32 + split
    gemm_f16s3<false, true, true><<<dim3(16, 16), blk, 0, stream>>>(
        H2_h, H2_l, W3t_h, W3t_l, b3, F_f32, F_h, F_l, 1024, 1024, 1024);
    // S = z @ CB^T : [4096, 512], K=256
    gemm_f16s3<false, true, false><<<dim3(8, 64), blk, 0, stream>>>(
        F_h, F_l, CB_h, CB_l, nullptr, S, nullptr, nullptr, 4096, 512, 256);

    vq_kernel<<<1024, blk, 0, stream>>>(F_f32, S, CB, cn, out, ls, idx_out);
    finalize_kernel<<<1, 1, 0, stream>>>(ls, loss_out);
}

// Round 3
// 137.189 us; speedup vs baseline: 2.4108x; 2.1889x over previous
//
#include <hip/hip_runtime.h>

// B=1024, D=1024 -> tokens N_TOK=4096, EMB=256, CODES=512.
// d_out (float32): out[1048576], loss[1], idx_as_float[4096].

typedef _Float16 half8 __attribute__((ext_vector_type(8)));
typedef _Float16 half4 __attribute__((ext_vector_type(4)));
typedef float floatx4 __attribute__((ext_vector_type(4)));

#define LO_SCALE 2048.0f
#define INV_LO_SCALE (1.0f / 2048.0f)

// LDS tile 64 rows x 64 halves (8KB). Granule (ks*4+g)^(row&7) holds
// k = ks*32 + 16h + 4g + j at half h*4+j.  (validated in round 2)
__device__ __forceinline__ void write_granules(
    _Float16* __restrict__ lds, int row, int ks, int g0, int hh, half4 a, half4 b)
{
    const int sw = row & 7, base = row * 64;
    *reinterpret_cast<half4*>(&lds[base + (((ks * 4 + g0)    ) ^ sw) * 8 + hh * 4]) = a;
    *reinterpret_cast<half4*>(&lds[base + (((ks * 4 + g0 + 1)) ^ sw) * 8 + hh * 4]) = b;
}

__device__ __forceinline__ half8 read_frag(
    const _Float16* __restrict__ lds, int row, int ks, int g)
{
    const int gr = (ks * 4 + g) ^ (row & 7);
    return *reinterpret_cast<const half8*>(&lds[row * 64 + gr * 8]);
}

// ---------------------------------------------------------------------------
// C = act(A @ B^T + bias), fp16 3-term split emulating fp32.
// A: [M][K] (f32 if AF32, else h/l f16).  B: h/l [N][K] f16 (pre-transposed).
// 512 thr / 8 waves; tile 64x64; wave tile 32x16 (2x1 frags of 16x16x32).
// Double-buffered LDS, 2-phase pipeline (load t+1 regs || compute t).
// ---------------------------------------------------------------------------
template <bool AF32, bool RELU, bool WF32, bool WSPLIT>
__global__ __launch_bounds__(512) void gemm_k(
    const float* __restrict__ Af,
    const _Float16* __restrict__ Ah, const _Float16* __restrict__ Al,
    const _Float16* __restrict__ Bh, const _Float16* __restrict__ Bl,
    const float* __restrict__ bias,
    float* __restrict__ Cf, _Float16* __restrict__ Ch, _Float16* __restrict__ Cl,
    int N, int K)
{
    __shared__ __align__(16) _Float16 sm[2][4][64 * 64];  // [buf][Ah,Al,Bh,Bl]

    const int tid = threadIdx.x;
    const int m0 = blockIdx.y * 64, n0 = blockIdx.x * 64;

    // staging mapping: one row per thread, one 16B octet of k
    const int so = tid & 7, srow = tid >> 3;          // srow 0..63
    const int ks_s = so >> 2, hh_s = (so >> 1) & 1, g0_s = (so & 1) * 2;
    const size_t aoff = (size_t)(m0 + srow) * K + so * 8;
    const size_t boff = (size_t)(n0 + srow) * K + so * 8;

    // wave mapping
    const int w = tid >> 6, l = tid & 63;
    const int wm = (w >> 2) * 32, wn = (w & 3) * 16;
    const int fr = l & 15, fg = l >> 4;

    float4 rA0, rA1;
    half8 rAh, rAl, rBh, rBl;

    auto LOAD = [&](int t) {
        const int kb = t * 64;
        if (AF32) {
            rA0 = *reinterpret_cast<const float4*>(&Af[aoff + kb]);
            rA1 = *reinterpret_cast<const float4*>(&Af[aoff + kb + 4]);
        } else {
            rAh = *reinterpret_cast<const half8*>(&Ah[aoff + kb]);
            rAl = *reinterpret_cast<const half8*>(&Al[aoff + kb]);
        }
        rBh = *reinterpret_cast<const half8*>(&Bh[boff + kb]);
        rBl = *reinterpret_cast<const half8*>(&Bl[boff + kb]);
    };

    auto WRITE = [&](int b) {
        half4 xa, xb;
        if (AF32) {
            float xs[8] = {rA0.x, rA0.y, rA0.z, rA0.w, rA1.x, rA1.y, rA1.z, rA1.w};
            half4 ha, hb, la, lb;
            #pragma unroll
            for (int j = 0; j < 4; ++j) {
                _Float16 hi = (_Float16)xs[j];
                ha[j] = hi; la[j] = (_Float16)((xs[j] - (float)hi) * LO_SCALE);
                hi = (_Float16)xs[4 + j];
                hb[j] = hi; lb[j] = (_Float16)((xs[4 + j] - (float)hi) * LO_SCALE);
            }
            write_granules(sm[b][0], srow, ks_s, g0_s, hh_s, ha, hb);
            write_granules(sm[b][1], srow, ks_s, g0_s, hh_s, la, lb);
        } else {
            #pragma unroll
            for (int j = 0; j < 4; ++j) { xa[j] = rAh[j]; xb[j] = rAh[j + 4]; }
            write_granules(sm[b][0], srow, ks_s, g0_s, hh_s, xa, xb);
            #pragma unroll
            for (int j = 0; j < 4; ++j) { xa[j] = rAl[j]; xb[j] = rAl[j + 4]; }
            write_granules(sm[b][1], srow, ks_s, g0_s, hh_s, xa, xb);
        }
        #pragma unroll
        for (int j = 0; j < 4; ++j) { xa[j] = rBh[j]; xb[j] = rBh[j + 4]; }
        write_granules(sm[b][2], srow, ks_s, g0_s, hh_s, xa, xb);
        #pragma unroll
        for (int j = 0; j < 4; ++j) { xa[j] = rBl[j]; xb[j] = rBl[j + 4]; }
        write_granules(sm[b][3], srow, ks_s, g0_s, hh_s, xa, xb);
    };

    floatx4 acc_hh[2] = {};
    floatx4 acc_mx[2] = {};

    const int NT = K >> 6;
    LOAD(0);
    WRITE(0);
    __syncthreads();

    for (int t = 0; t < NT; ++t) {
        const int cur = t & 1;
        if (t + 1 < NT) LOAD(t + 1);   // global->reg, latency hides under MFMA
        #pragma unroll
        for (int ks = 0; ks < 2; ++ks) {
            half8 a_h[2], a_l[2], b_h, b_l;
            #pragma unroll
            for (int i = 0; i < 2; ++i) {
                a_h[i] = read_frag(sm[cur][0], wm + i * 16 + fr, ks, fg);
                a_l[i] = read_frag(sm[cur][1], wm + i * 16 + fr, ks, fg);
            }
            b_h = read_frag(sm[cur][2], wn + fr, ks, fg);
            b_l = read_frag(sm[cur][3], wn + fr, ks, fg);
            #pragma unroll
            for (int i = 0; i < 2; ++i) {
                acc_hh[i] = __builtin_amdgcn_mfma_f32_16x16x32_f16(a_h[i], b_h, acc_hh[i], 0, 0, 0);
                acc_mx[i] = __builtin_amdgcn_mfma_f32_16x16x32_f16(a_h[i], b_l, acc_mx[i], 0, 0, 0);
                acc_mx[i] = __builtin_amdgcn_mfma_f32_16x16x32_f16(a_l[i], b_h, acc_mx[i], 0, 0, 0);
            }
        }
        if (t + 1 < NT) WRITE(cur ^ 1);  // vmcnt wait folds in here
        __syncthreads();                 // one barrier per K-iter
    }

    // Epilogue. C/D layout: col = lane&15, row = 4*(lane>>4) + reg.
    const int col = n0 + wn + fr;
    const float bv = bias ? bias[col] : 0.0f;
    #pragma unroll
    for (int i = 0; i < 2; ++i) {
        #pragma unroll
        for (int r = 0; r < 4; ++r) {
            const int row = m0 + wm + i * 16 + fg * 4 + r;
            float v = acc_hh[i][r] + acc_mx[i][r] * INV_LO_SCALE + bv;
            if (RELU) v = fmaxf(v, 0.0f);
            const size_t o = (size_t)row * N + col;
            if (WF32) Cf[o] = v;
            if (WSPLIT) {
                const _Float16 hi = (_Float16)v;
                Ch[o] = hi;
                Cl[o] = (_Float16)((v - (float)hi) * LO_SCALE);
            }
        }
    }
}

// ---------------------------------------------------------------------------
// Split + transpose all three weights: W [1024][1024] f32 -> [N][K] h/l f16.
// ---------------------------------------------------------------------------
__global__ __launch_bounds__(256) void splitT3_kernel(
    const float* __restrict__ W1, const float* __restrict__ W2, const float* __restrict__ W3,
    _Float16* __restrict__ T1h, _Float16* __restrict__ T1l,
    _Float16* __restrict__ T2h, _Float16* __restrict__ T2l,
    _Float16* __restrict__ T3h, _Float16* __restrict__ T3l)
{
    const int z = blockIdx.z;
    const float* Wm = (z == 0) ? W1 : (z == 1) ? W2 : W3;
    _Float16* Th = (z == 0) ? T1h : (z == 1) ? T2h : T3h;
    _Float16* Tl = (z == 0) ? T1l : (z == 1) ? T2l : T3l;

    __shared__ float tile[64][65];
    const int tid = threadIdx.x;
    const int kb = blockIdx.y * 64, nb = blockIdx.x * 64;
    {
        const int kr = tid >> 2, c0 = (tid & 3) * 16;
        #pragma unroll
        for (int c = 0; c < 16; c += 4) {
            float4 v = *reinterpret_cast<const float4*>(
                &Wm[(size_t)(kb + kr) * 1024 + nb + c0 + c]);
            tile[kr][c0 + c] = v.x; tile[kr][c0 + c + 1] = v.y;
            tile[kr][c0 + c + 2] = v.z; tile[kr][c0 + c + 3] = v.w;
        }
    }
    __syncthreads();
    {
        const int nr = tid >> 2, k0 = (tid & 3) * 16;
        half8 h[2], lo[2];
        #pragma unroll
        for (int c = 0; c < 16; ++c) {
            const float x = tile[k0 + c][nr];
            const _Float16 hi = (_Float16)x;
            h[c >> 3][c & 7] = hi;
            lo[c >> 3][c & 7] = (_Float16)((x - (float)hi) * LO_SCALE);
        }
        const size_t o = (size_t)(nb + nr) * 1024 + kb + k0;
        *reinterpret_cast<half8*>(&Th[o]) = h[0];
        *reinterpret_cast<half8*>(&Th[o + 8]) = h[1];
        *reinterpret_cast<half8*>(&Tl[o]) = lo[0];
        *reinterpret_cast<half8*>(&Tl[o + 8]) = lo[1];
    }
}

// ---------------------------------------------------------------------------
// Codebook split + squared norms. One wave per code.
// ---------------------------------------------------------------------------
__global__ void cb_split_kernel(const float* __restrict__ CB,
                                _Float16* __restrict__ CBh, _Float16* __restrict__ CBl,
                                float* __restrict__ cnorm)
{
    const int k = blockIdx.x, lane = threadIdx.x;  // 64
    const int i = k * 256 + lane * 4;
    float4 c = *reinterpret_cast<const float4*>(&CB[i]);
    float xs[4] = {c.x, c.y, c.z, c.w};
    half4 h, lo;
    float s = 0.f;
    #pragma unroll
    for (int j = 0; j < 4; ++j) {
        const _Float16 hi = (_Float16)xs[j];
        h[j] = hi;
        lo[j] = (_Float16)((xs[j] - (float)hi) * LO_SCALE);
        s += xs[j] * xs[j];
    }
    *reinterpret_cast<half4*>(&CBh[i]) = h;
    *reinterpret_cast<half4*>(&CBl[i]) = lo;
    #pragma unroll
    for (int off = 32; off; off >>= 1) s += __shfl_down(s, off);
    if (lane == 0) cnorm[k] = s;
}

// ---------------------------------------------------------------------------
// VQ: one wave per token; 8 tokens per 512-thr block. Per-block loss partial.
// ---------------------------------------------------------------------------
__global__ __launch_bounds__(512) void vq_kernel(
    const _Float16* __restrict__ Fh, const _Float16* __restrict__ Fl,
    const float* __restrict__ S, const float* __restrict__ CB,
    const float* __restrict__ cnorm,
    float* __restrict__ out, float* __restrict__ pl, float* __restrict__ idx_out)
{
    const int wid = threadIdx.x >> 6, lane = threadIdx.x & 63;
    const int n = blockIdx.x * 8 + wid;

    float best = 3.4e38f;
    int bidx = 0x7fffffff;
    #pragma unroll
    for (int j = 0; j < 8; ++j) {
        const int k = j * 64 + lane;
        const float v = fmaf(-2.0f, S[(size_t)n * 512 + k], cnorm[k]);
        if (v < best) { best = v; bidx = k; }   // strict <: first occurrence
    }
    #pragma unroll
    for (int off = 32; off; off >>= 1) {
        const float ov = __shfl_down(best, off);
        const int oi = __shfl_down(bidx, off);
        if (ov < best || (ov == best && oi < bidx)) { best = ov; bidx = oi; }
    }
    bidx = __shfl(bidx, 0);
    best = __shfl(best, 0);

    // ||z||^2 from split reconstruction
    const int base = n * 256 + lane * 4;
    half4 h4 = *reinterpret_cast<const half4*>(&Fh[base]);
    half4 l4 = *reinterpret_cast<const half4*>(&Fl[base]);
    float zn = 0.f;
    #pragma unroll
    for (int j = 0; j < 4; ++j) {
        const float z = (float)h4[j] + (float)l4[j] * INV_LO_SCALE;
        zn = fmaf(z, z, zn);
    }
    #pragma unroll
    for (int off = 32; off; off >>= 1) zn += __shfl_down(zn, off);

    float4 q4 = *reinterpret_cast<const float4*>(&CB[(size_t)bidx * 256 + lane * 4]);
    *reinterpret_cast<float4*>(&out[(size_t)n * 256 + lane * 4]) = q4;

    __shared__ float part[8];
    if (lane == 0) {
        part[wid] = zn + best;      // = ||z - q||^2 for this token
        idx_out[n] = (float)bidx;
    }
    __syncthreads();
    if (threadIdx.x == 0) {
        float s = 0.f;
        #pragma unroll
        for (int i = 0; i < 8; ++i) s += part[i];
        pl[blockIdx.x] = s;
    }
}

__global__ __launch_bounds__(512) void finalize_kernel(
    const float* __restrict__ pl, float* __restrict__ loss_out)
{
    float s = pl[threadIdx.x];
    #pragma unroll
    for (int off = 32; off; off >>= 1) s += __shfl_down(s, off);
    __shared__ float p[8];
    if ((threadIdx.x & 63) == 0) p[threadIdx.x >> 6] = s;
    __syncthreads();
    if (threadIdx.x == 0) {
        float t = 0.f;
        #pragma unroll
        for (int i = 0; i < 8; ++i) t += p[i];
        loss_out[0] = 1.25f * t / 1048576.0f;
    }
}

// ---------------------------------------------------------------------------
extern "C" void kernel_launch(void* const* d_in, const int* in_sizes, int n_in,
                              void* d_out, int out_size, void* d_ws, size_t ws_size,
                              hipStream_t stream)
{
    const float* obs = (const float*)d_in[0];
    const float* W1  = (const float*)d_in[1];
    const float* b1  = (const float*)d_in[2];
    const float* W2  = (const float*)d_in[3];
    const float* b2  = (const float*)d_in[4];
    const float* W3  = (const float*)d_in[5];
    const float* b3  = (const float*)d_in[6];
    const float* CB  = (const float*)d_in[7];

    float* out = (float*)d_out;
    float* loss_out = out + 1048576;
    float* idx_out  = out + 1048577;

    char* Wp = (char*)d_ws;
    _Float16* W1t_h = (_Float16*)(Wp + (0u  << 20));
    _Float16* W1t_l = (_Float16*)(Wp + (2u  << 20));
    _Float16* W2t_h = (_Float16*)(Wp + (4u  << 20));
    _Float16* W2t_l = (_Float16*)(Wp + (6u  << 20));
    float*    S     = (float*)(Wp + (0u << 20));      // 8MB, after L2 done
    _Float16* W3t_h = (_Float16*)(Wp + (8u  << 20));
    _Float16* W3t_l = (_Float16*)(Wp + (10u << 20));
    _Float16* H1_h  = (_Float16*)(Wp + (12u << 20));
    _Float16* H1_l  = (_Float16*)(Wp + (14u << 20));
    _Float16* H2_h  = (_Float16*)(Wp + (16u << 20));
    _Float16* H2_l  = (_Float16*)(Wp + (18u << 20));
    _Float16* F_h   = (_Float16*)(Wp + (20u << 20));
    _Float16* F_l   = (_Float16*)(Wp + (22u << 20));
    _Float16* CB_h  = (_Float16*)(Wp + (24u << 20));
    _Float16* CB_l  = (_Float16*)(Wp + (24u << 20) + 512 * 256 * 2);
    float*    cn    = (float*)(Wp + (24u << 20) + 2 * 512 * 256 * 2);
    float*    pl    = cn + 512;

    splitT3_kernel<<<dim3(16, 16, 3), 256, 0, stream>>>(
        W1, W2, W3, W1t_h, W1t_l, W2t_h, W2t_l, W3t_h, W3t_l);
    cb_split_kernel<<<512, 64, 0, stream>>>(CB, CB_h, CB_l, cn);

    // L1: A = obs (fp32, split in staging)
    gemm_k<true, true, false, true><<<dim3(16, 16), 512, 0, stream>>>(
        obs, nullptr, nullptr, W1t_h, W1t_l, b1, nullptr, H1_h, H1_l, 1024, 1024);
    // L2
    gemm_k<false, true, false, true><<<dim3(16, 16), 512, 0, stream>>>(
        nullptr, H1_h, H1_l, W2t_h, W2t_l, b2, nullptr, H2_h, H2_l, 1024, 1024);
    // L3 -> F (split only; z reconstructed from h/l downstream)
    gemm_k<false, false, false, true><<<dim3(16, 16), 512, 0, stream>>>(
        nullptr, H2_h, H2_l, W3t_h, W3t_l, b3, nullptr, F_h, F_l, 1024, 1024);
    // S = z @ CB^T : [4096, 512], K=256  (overwrites W1t/W2t region — dead)
    gemm_k<false, false, true, false><<<dim3(8, 64), 512, 0, stream>>>(
        nullptr, F_h, F_l, CB_h, CB_l, nullptr, S, nullptr, nullptr, 512, 256);

    vq_kernel<<<512, 512, 0, stream>>>(F_h, F_l, S, CB, cn, out, pl, idx_out);
    finalize_kernel<<<1, 512, 0, stream>>>(pl, loss_out);
}